// Round 1
// baseline (291.491 us; speedup 1.0000x reference)
//
#include <hip/hip_runtime.h>
#include <stdint.h>

#define B_ 4
#define S_ 4096
#define D_ 1024
#define E_ 2048          // 2*D
#define K_ 1024
#define M_ (B_*S_)       // 16384
#define SEG 128
#define NSEG (S_/SEG)    // 32

typedef __bf16 bf16x8 __attribute__((ext_vector_type(8)));
typedef float  f32x4  __attribute__((ext_vector_type(4)));

__device__ __forceinline__ unsigned short f2bf(float f) {
    union { float f; unsigned int u; } x; x.f = f;
    unsigned int u = x.u;
    return (unsigned short)((u + 0x7fffu + ((u >> 16) & 1u)) >> 16);
}

__device__ __forceinline__ float sigmoidf_(float x) {
    return 1.0f / (1.0f + __expf(-x));
}

__device__ __forceinline__ void gload16(const void* g, void* l) {
    __builtin_amdgcn_global_load_lds(
        (const __attribute__((address_space(1))) void*)(uintptr_t)g,
        (__attribute__((address_space(3))) void*)(uintptr_t)l,
        16, 0, 0);
}

// ---------------- conversion kernels ----------------
__global__ void cvt_x(const float* __restrict__ x, unsigned short* __restrict__ xb, int n) {
    int i = (blockIdx.x * blockDim.x + threadIdx.x) * 4;
    if (i >= n) return;
    float4 f = *(const float4*)(x + i);
    ushort4 o;
    o.x = f2bf(f.x); o.y = f2bf(f.y); o.z = f2bf(f.z); o.w = f2bf(f.w);
    *(ushort4*)(xb + i) = o;
}

// W' row 2d+g  <-  W row g*D + d   (interleave hidden/gate rows)
__global__ void cvt_w(const float* __restrict__ w, unsigned short* __restrict__ wb) {
    int i = (blockIdx.x * blockDim.x + threadIdx.x) * 4;  // output index into [E_, K_]
    int r = i >> 10;            // K_ = 1024
    int k = i & 1023;
    int d = r >> 1, g = r & 1;
    const float* src = w + (size_t)(g * D_ + d) * K_ + k;
    float4 f = *(const float4*)src;
    ushort4 o;
    o.x = f2bf(f.x); o.y = f2bf(f.y); o.z = f2bf(f.z); o.w = f2bf(f.w);
    *(ushort4*)(wb + i) = o;
}

// ---------------- GEMM + fused epilogue ----------------
// C[m,e'] = sum_k Xb[m,k] * Wb[e',k]   (both row-major, K contiguous)
// epilogue: pair even/odd e' columns -> c = sigmoid(-gate), v = sigmoid(gate)*g(hidden)
#define BM 128
#define BN 128
#define BK 32

__global__ __launch_bounds__(256, 2)
void gemm_ep(const unsigned short* __restrict__ xb,
             const unsigned short* __restrict__ wb,
             float* __restrict__ cArr, float* __restrict__ vArr) {
    __shared__ unsigned short As[BM * BK];   // 8 KB
    __shared__ unsigned short Bs[BN * BK];   // 8 KB

    const int tid  = threadIdx.x;
    const int lane = tid & 63;
    const int w    = tid >> 6;
    const int mBase = blockIdx.y * BM;
    const int eBase = blockIdx.x * BN;
    const int waveM = (w >> 1) * 64;
    const int waveN = (w & 1) * 64;

    f32x4 acc[4][4] = {};

    // staging addressing: 16B unit u = r0*256 + tid ; row = u>>2 ; cu = u&3
    const int row0 = tid >> 2, cu = tid & 3;
    const unsigned short* aG0 = xb + (size_t)(mBase + row0) * K_ + cu * 8;
    const unsigned short* aG1 = aG0 + (size_t)64 * K_;
    const unsigned short* bG0 = wb + (size_t)(eBase + row0) * K_ + cu * 8;
    const unsigned short* bG1 = bG0 + (size_t)64 * K_;
    // wave-uniform LDS bases (HW adds lane*16B)
    unsigned short* aL0 = As + (size_t)(w * 64) * 8;
    unsigned short* aL1 = As + (size_t)(256 + w * 64) * 8;
    unsigned short* bL0 = Bs + (size_t)(w * 64) * 8;
    unsigned short* bL1 = Bs + (size_t)(256 + w * 64) * 8;

    const int mrow = lane & 15;
    const int kg   = (lane >> 4) * 8;   // element offset along K within row

    for (int k0 = 0; k0 < K_; k0 += BK) {
        __syncthreads();
        gload16(aG0 + k0, aL0);
        gload16(aG1 + k0, aL1);
        gload16(bG0 + k0, bL0);
        gload16(bG1 + k0, bL1);
        __syncthreads();

        bf16x8 af[4], bf[4];
#pragma unroll
        for (int i = 0; i < 4; i++)
            af[i] = *(const bf16x8*)(As + (size_t)(waveM + i * 16 + mrow) * BK + kg);
#pragma unroll
        for (int j = 0; j < 4; j++)
            bf[j] = *(const bf16x8*)(Bs + (size_t)(waveN + j * 16 + mrow) * BK + kg);
#pragma unroll
        for (int i = 0; i < 4; i++)
#pragma unroll
            for (int j = 0; j < 4; j++)
                acc[i][j] = __builtin_amdgcn_mfma_f32_16x16x32_bf16(af[i], bf[j], acc[i][j], 0, 0, 0);
    }

    // epilogue: C/D layout col = lane&15, row = (lane>>4)*4 + r
    const int nloc  = lane & 15;
    const int rquad = (lane >> 4) * 4;
    const bool isGate = (nloc & 1);
#pragma unroll
    for (int i = 0; i < 4; i++) {
#pragma unroll
        for (int j = 0; j < 4; j++) {
            int e = eBase + waveN + j * 16 + nloc;
            int d = e >> 1;
#pragma unroll
            for (int r = 0; r < 4; r++) {
                int m = mBase + waveM + i * 16 + rquad + r;
                float val = acc[i][j][r];
                float other = __shfl_xor(val, 1, 64);
                if (!isGate) {
                    // val = hidden, other = gate
                    float g = (val >= 0.f) ? (val + 0.5f) : sigmoidf_(val);
                    vArr[(size_t)m * D_ + d] = sigmoidf_(other) * g;
                } else {
                    // val = gate
                    cArr[(size_t)m * D_ + d] = sigmoidf_(-val);
                }
            }
        }
    }
}

// ---------------- blocked scan: h_t = c_t*h_{t-1} + v_t ----------------
__global__ void seg_reduce(const float* __restrict__ cArr, const float* __restrict__ vArr,
                           float* __restrict__ segC, float* __restrict__ segV) {
    int bj = blockIdx.x;                 // b*NSEG + j
    int b = bj / NSEG, j = bj % NSEG;
    int d = blockIdx.y * 256 + threadIdx.x;
    size_t base = ((size_t)b * S_ + (size_t)j * SEG) * D_ + d;
    float C = 1.f, V = 0.f;
    for (int s = 0; s < SEG; s++) {
        float cc = cArr[base + (size_t)s * D_];
        float vv = vArr[base + (size_t)s * D_];
        V = fmaf(cc, V, vv);
        C *= cc;
    }
    segC[(size_t)bj * D_ + d] = C;
    segV[(size_t)bj * D_ + d] = V;
}

__global__ void seg_scan(const float* __restrict__ segC, const float* __restrict__ segV,
                         float* __restrict__ segH) {
    int b = blockIdx.x;
    int d = blockIdx.y * 256 + threadIdx.x;
    float h = 0.f;
    for (int j = 0; j < NSEG; j++) {
        size_t idx = ((size_t)b * NSEG + j) * D_ + d;
        segH[idx] = h;
        h = fmaf(segC[idx], h, segV[idx]);
    }
}

__global__ void seg_apply(const float* __restrict__ cArr, const float* __restrict__ vArr,
                          const float* __restrict__ segH, float* __restrict__ out) {
    int bj = blockIdx.x;
    int b = bj / NSEG, j = bj % NSEG;
    int d = blockIdx.y * 256 + threadIdx.x;
    float h = segH[(size_t)bj * D_ + d];
    size_t base = ((size_t)b * S_ + (size_t)j * SEG) * D_ + d;
    for (int s = 0; s < SEG; s++) {
        float cc = cArr[base + (size_t)s * D_];
        float vv = vArr[base + (size_t)s * D_];
        h = fmaf(cc, h, vv);
        out[base + (size_t)s * D_] = h;
    }
}

// ---------------- launch ----------------
extern "C" void kernel_launch(void* const* d_in, const int* in_sizes, int n_in,
                              void* d_out, int out_size, void* d_ws, size_t ws_size,
                              hipStream_t stream) {
    const float* x = (const float*)d_in[0];
    const float* wmat = (const float*)d_in[1];
    float* out = (float*)d_out;
    char* ws = (char*)d_ws;

    unsigned short* xb   = (unsigned short*)(ws);                 // 32 MB
    unsigned short* wb   = (unsigned short*)(ws + 33554432);      //  4 MB
    float* cArr = (float*)(ws + 37748736);                        // 64 MB
    float* vArr = (float*)(ws + 104857600);                       // 64 MB
    float* segC = (float*)(ws + 171966464);                       // 512 KB
    float* segV = (float*)(ws + 172490752);                       // 512 KB
    float* segH = (float*)(ws + 173015040);                       // 512 KB

    cvt_x<<<(M_ * K_) / 1024, 256, 0, stream>>>(x, xb, M_ * K_);
    cvt_w<<<(E_ * K_) / 1024, 256, 0, stream>>>(wmat, wb);

    dim3 gg(E_ / BN, M_ / BM);
    gemm_ep<<<gg, 256, 0, stream>>>(xb, wb, cArr, vArr);

    dim3 ga(B_ * NSEG, D_ / 256);
    seg_reduce<<<ga, 256, 0, stream>>>(cArr, vArr, segC, segV);
    dim3 gb(B_, D_ / 256);
    seg_scan<<<gb, 256, 0, stream>>>(segC, segV, segH);
    seg_apply<<<ga, 256, 0, stream>>>(cArr, vArr, segH, out);
}

// Round 2
// 270.275 us; speedup vs baseline: 1.0785x; 1.0785x over previous
//
#include <hip/hip_runtime.h>
#include <stdint.h>

#define B_ 4
#define S_ 4096
#define D_ 1024
#define E_ 2048          // 2*D
#define K_ 1024
#define M_ (B_*S_)       // 16384
#define SEG 64
#define NSEG (S_/SEG)    // 64

typedef __bf16 bf16x8 __attribute__((ext_vector_type(8)));
typedef float  f32x4  __attribute__((ext_vector_type(4)));
typedef _Float16 f16x2 __attribute__((ext_vector_type(2)));

__device__ __forceinline__ unsigned short f2bf(float f) {
    union { float f; unsigned int u; } x; x.f = f;
    unsigned int u = x.u;
    return (unsigned short)((u + 0x7fffu + ((u >> 16) & 1u)) >> 16);
}

__device__ __forceinline__ float sigmoidf_(float x) {
    return 1.0f / (1.0f + __expf(-x));
}

__device__ __forceinline__ void gload16(const void* g, void* l) {
    __builtin_amdgcn_global_load_lds(
        (const __attribute__((address_space(1))) void*)(uintptr_t)g,
        (__attribute__((address_space(3))) void*)(uintptr_t)l,
        16, 0, 0);
}

// ---------------- conversion kernels ----------------
__global__ void cvt_x(const float* __restrict__ x, unsigned short* __restrict__ xb, int n) {
    int i = (blockIdx.x * blockDim.x + threadIdx.x) * 4;
    if (i >= n) return;
    float4 f = *(const float4*)(x + i);
    ushort4 o;
    o.x = f2bf(f.x); o.y = f2bf(f.y); o.z = f2bf(f.z); o.w = f2bf(f.w);
    *(ushort4*)(xb + i) = o;
}

// W' row 2d+g  <-  W row g*D + d   (interleave hidden/gate rows)
__global__ void cvt_w(const float* __restrict__ w, unsigned short* __restrict__ wb) {
    int i = (blockIdx.x * blockDim.x + threadIdx.x) * 4;  // output index into [E_, K_]
    int r = i >> 10;            // K_ = 1024
    int k = i & 1023;
    int d = r >> 1, g = r & 1;
    const float* src = w + (size_t)(g * D_ + d) * K_ + k;
    float4 f = *(const float4*)src;
    ushort4 o;
    o.x = f2bf(f.x); o.y = f2bf(f.y); o.z = f2bf(f.z); o.w = f2bf(f.w);
    *(ushort4*)(wb + i) = o;
}

// ---------------- GEMM + fused epilogue ----------------
// C[m,e'] = sum_k Xb[m,k] * Wb[e',k]   (both row-major, K contiguous)
// LDS layout XOR-swizzled: chunk c (16B) of tile-row r stored at slot c^((r>>2)&3)
// -> fragment ds_read_b128 is 2-way-per-bank-group (free) instead of 8-way.
#define BM 128
#define BN 128
#define BK 32

__global__ __launch_bounds__(256, 2)
void gemm_ep(const unsigned short* __restrict__ xb,
             const unsigned short* __restrict__ wb,
             _Float16* __restrict__ cArr, _Float16* __restrict__ vArr) {
    __shared__ unsigned short As[BM * BK];   // 8 KB
    __shared__ unsigned short Bs[BN * BK];   // 8 KB

    const int tid  = threadIdx.x;
    const int lane = tid & 63;
    const int w    = tid >> 6;
    const int mBase = blockIdx.y * BM;
    const int eBase = blockIdx.x * BN;
    const int waveM = (w >> 1) * 64;
    const int waveN = (w & 1) * 64;

    f32x4 acc[4][4] = {};

    // staging: lane tid covers (row = tid>>2, slot = tid&3); fetch global chunk
    // slot ^ ((row>>2)&3)  — ((tid>>4)&3) equals (tile_row>>2)&3 for both halves.
    const int row0 = tid >> 2;
    const int cu   = (tid & 3) ^ ((tid >> 4) & 3);
    const unsigned short* aG0 = xb + (size_t)(mBase + row0) * K_ + cu * 8;
    const unsigned short* aG1 = aG0 + (size_t)64 * K_;
    const unsigned short* bG0 = wb + (size_t)(eBase + row0) * K_ + cu * 8;
    const unsigned short* bG1 = bG0 + (size_t)64 * K_;
    // wave-uniform LDS bases (HW adds lane*16B)
    unsigned short* aL0 = As + (size_t)(w * 64) * 8;
    unsigned short* aL1 = As + (size_t)(256 + w * 64) * 8;
    unsigned short* bL0 = Bs + (size_t)(w * 64) * 8;
    unsigned short* bL1 = Bs + (size_t)(256 + w * 64) * 8;

    const int mrow = lane & 15;
    // logical K-chunk q = lane>>4 lives at slot q ^ ((mrow>>2)&3)
    const int kOff = (((lane >> 4) ^ ((lane >> 2) & 3)) & 3) * 8;

    for (int k0 = 0; k0 < K_; k0 += BK) {
        __syncthreads();
        gload16(aG0 + k0, aL0);
        gload16(aG1 + k0, aL1);
        gload16(bG0 + k0, bL0);
        gload16(bG1 + k0, bL1);
        __syncthreads();

        bf16x8 af[4], bf[4];
#pragma unroll
        for (int i = 0; i < 4; i++)
            af[i] = *(const bf16x8*)(As + (size_t)(waveM + i * 16 + mrow) * BK + kOff);
#pragma unroll
        for (int j = 0; j < 4; j++)
            bf[j] = *(const bf16x8*)(Bs + (size_t)(waveN + j * 16 + mrow) * BK + kOff);
#pragma unroll
        for (int i = 0; i < 4; i++)
#pragma unroll
            for (int j = 0; j < 4; j++)
                acc[i][j] = __builtin_amdgcn_mfma_f32_16x16x32_bf16(af[i], bf[j], acc[i][j], 0, 0, 0);
    }

    // epilogue: C/D layout col = lane&15, row = (lane>>4)*4 + r
    const int nloc  = lane & 15;
    const int rquad = (lane >> 4) * 4;
    const bool isGate = (nloc & 1);
#pragma unroll
    for (int i = 0; i < 4; i++) {
#pragma unroll
        for (int j = 0; j < 4; j++) {
            int e = eBase + waveN + j * 16 + nloc;
            int d = e >> 1;
#pragma unroll
            for (int r = 0; r < 4; r++) {
                int m = mBase + waveM + i * 16 + rquad + r;
                float val = acc[i][j][r];
                float other = __shfl_xor(val, 1, 64);
                if (!isGate) {
                    // val = hidden, other = gate
                    float g = (val >= 0.f) ? (val + 0.5f) : sigmoidf_(val);
                    vArr[(size_t)m * D_ + d] = (_Float16)(sigmoidf_(other) * g);
                } else {
                    // val = gate
                    cArr[(size_t)m * D_ + d] = (_Float16)sigmoidf_(-val);
                }
            }
        }
    }
}

// ---------------- blocked scan: h_t = c_t*h_{t-1} + v_t ----------------
// column-pair granularity: thread handles d = 2p, 2p+1 via f16x2 loads.
__global__ void seg_reduce(const f16x2* __restrict__ c2, const f16x2* __restrict__ v2,
                           float2* __restrict__ segC, float2* __restrict__ segV) {
    int bj = blockIdx.x;                          // b*NSEG + j  (row block start = bj*SEG)
    int p = blockIdx.y * 256 + threadIdx.x;       // 0..511
    size_t base = (size_t)bj * SEG * (D_ / 2) + p;
    float C0 = 1.f, V0 = 0.f, C1 = 1.f, V1 = 0.f;
#pragma unroll 4
    for (int s = 0; s < SEG; s++) {
        f16x2 cc = c2[base + (size_t)s * (D_ / 2)];
        f16x2 vv = v2[base + (size_t)s * (D_ / 2)];
        float c0 = (float)cc[0], c1 = (float)cc[1];
        V0 = fmaf(c0, V0, (float)vv[0]);
        V1 = fmaf(c1, V1, (float)vv[1]);
        C0 *= c0; C1 *= c1;
    }
    segC[(size_t)bj * (D_ / 2) + p] = make_float2(C0, C1);
    segV[(size_t)bj * (D_ / 2) + p] = make_float2(V0, V1);
}

__global__ void seg_scan(const float2* __restrict__ segC, const float2* __restrict__ segV,
                         float2* __restrict__ segH) {
    int b = blockIdx.x;
    int p = blockIdx.y * 256 + threadIdx.x;
    float h0 = 0.f, h1 = 0.f;
    for (int j = 0; j < NSEG; j++) {
        size_t idx = ((size_t)b * NSEG + j) * (D_ / 2) + p;
        segH[idx] = make_float2(h0, h1);
        float2 c = segC[idx], v = segV[idx];
        h0 = fmaf(c.x, h0, v.x);
        h1 = fmaf(c.y, h1, v.y);
    }
}

__global__ void seg_apply(const f16x2* __restrict__ c2, const f16x2* __restrict__ v2,
                          const float2* __restrict__ segH, float2* __restrict__ out) {
    int bj = blockIdx.x;
    int p = blockIdx.y * 256 + threadIdx.x;
    float2 h = segH[(size_t)bj * (D_ / 2) + p];
    float h0 = h.x, h1 = h.y;
    size_t base = (size_t)bj * SEG * (D_ / 2) + p;
#pragma unroll 4
    for (int s = 0; s < SEG; s++) {
        f16x2 cc = c2[base + (size_t)s * (D_ / 2)];
        f16x2 vv = v2[base + (size_t)s * (D_ / 2)];
        h0 = fmaf((float)cc[0], h0, (float)vv[0]);
        h1 = fmaf((float)cc[1], h1, (float)vv[1]);
        out[base + (size_t)s * (D_ / 2)] = make_float2(h0, h1);
    }
}

// ---------------- launch ----------------
extern "C" void kernel_launch(void* const* d_in, const int* in_sizes, int n_in,
                              void* d_out, int out_size, void* d_ws, size_t ws_size,
                              hipStream_t stream) {
    const float* x = (const float*)d_in[0];
    const float* wmat = (const float*)d_in[1];
    float* out = (float*)d_out;
    char* ws = (char*)d_ws;

    unsigned short* xb = (unsigned short*)(ws);                   // 32 MB @ 0
    unsigned short* wb = (unsigned short*)(ws + (32u << 20));     //  4 MB @ 32M
    _Float16* cArr = (_Float16*)(ws + (36u << 20));               // 32 MB @ 36M
    _Float16* vArr = (_Float16*)(ws + (68u << 20));               // 32 MB @ 68M
    float* segC = (float*)(ws + (100u << 20));                    //  1 MB @ 100M
    float* segV = (float*)(ws + (101u << 20));                    //  1 MB @ 101M
    float* segH = (float*)(ws + (102u << 20));                    //  1 MB @ 102M

    cvt_x<<<(M_ * K_) / 1024, 256, 0, stream>>>(x, xb, M_ * K_);
    cvt_w<<<(E_ * K_) / 1024, 256, 0, stream>>>(wmat, wb);

    dim3 gg(E_ / BN, M_ / BM);
    gemm_ep<<<gg, 256, 0, stream>>>(xb, wb, cArr, vArr);

    dim3 ga(B_ * NSEG, D_ / 512);
    seg_reduce<<<ga, 256, 0, stream>>>((const f16x2*)cArr, (const f16x2*)vArr,
                                       (float2*)segC, (float2*)segV);
    dim3 gb(B_, D_ / 512);
    seg_scan<<<gb, 256, 0, stream>>>((const float2*)segC, (const float2*)segV, (float2*)segH);
    seg_apply<<<ga, 256, 0, stream>>>((const f16x2*)cArr, (const f16x2*)vArr,
                                      (const float2*)segH, (float2*)out);
}

// Round 3
// 247.046 us; speedup vs baseline: 1.1799x; 1.0940x over previous
//
#include <hip/hip_runtime.h>
#include <stdint.h>

#define B_ 4
#define S_ 4096
#define D_ 1024
#define E_ 2048          // 2*D
#define K_ 1024
#define M_ (B_*S_)       // 16384
#define SEG 64
#define NSEG (S_/SEG)    // 64

typedef __bf16 bf16x8 __attribute__((ext_vector_type(8)));
typedef float  f32x4  __attribute__((ext_vector_type(4)));
typedef _Float16 f16x2 __attribute__((ext_vector_type(2)));

__device__ __forceinline__ unsigned short f2bf(float f) {
    union { float f; unsigned int u; } x; x.f = f;
    unsigned int u = x.u;
    return (unsigned short)((u + 0x7fffu + ((u >> 16) & 1u)) >> 16);
}

__device__ __forceinline__ void gload16(const void* g, void* l) {
    __builtin_amdgcn_global_load_lds(
        (const __attribute__((address_space(1))) void*)(uintptr_t)g,
        (__attribute__((address_space(3))) void*)(uintptr_t)l,
        16, 0, 0);
}

// pack (c = sigmoid(-gate), v = sigmoid(gate)*g(hidden)) as half2 in a uint
__device__ __forceinline__ unsigned int packCV(float hid, float gat) {
    float e  = __expf(gat);
    float c  = __builtin_amdgcn_rcpf(1.f + e);          // sigmoid(-gate)
    float gg = (hid >= 0.f) ? (hid + 0.5f)
                            : __builtin_amdgcn_rcpf(1.f + __expf(-hid));
    float v  = (1.f - c) * gg;                           // sigmoid(gate)*g(hidden)
    union { f16x2 h; unsigned int u; } pk;
    pk.h[0] = (_Float16)c; pk.h[1] = (_Float16)v;
    return pk.u;
}

// ---------------- conversion kernels ----------------
__global__ void cvt_x(const float* __restrict__ x, unsigned short* __restrict__ xb, int n) {
    int i = (blockIdx.x * blockDim.x + threadIdx.x) * 4;
    if (i >= n) return;
    float4 f = *(const float4*)(x + i);
    ushort4 o;
    o.x = f2bf(f.x); o.y = f2bf(f.y); o.z = f2bf(f.z); o.w = f2bf(f.w);
    *(ushort4*)(xb + i) = o;
}

// W' row 2d+g  <-  W row g*D + d   (interleave hidden/gate rows)
__global__ void cvt_w(const float* __restrict__ w, unsigned short* __restrict__ wb) {
    int i = (blockIdx.x * blockDim.x + threadIdx.x) * 4;
    int r = i >> 10;            // K_ = 1024
    int k = i & 1023;
    int d = r >> 1, g = r & 1;
    const float* src = w + (size_t)(g * D_ + d) * K_ + k;
    float4 f = *(const float4*)src;
    ushort4 o;
    o.x = f2bf(f.x); o.y = f2bf(f.y); o.z = f2bf(f.z); o.w = f2bf(f.w);
    *(ushort4*)(wb + i) = o;
}

// ---------------- GEMM + fused epilogue ----------------
#define BM 128
#define BN 128
#define BK 32

__global__ __launch_bounds__(256, 2)
void gemm_ep(const unsigned short* __restrict__ xb,
             const unsigned short* __restrict__ wb,
             unsigned int* __restrict__ cv) {
    __shared__ unsigned short As[BM * BK];                 // 8 KB
    __shared__ unsigned short Bs[BN * BK];                 // 8 KB
    __shared__ __align__(16) unsigned int Ep[4][64][36];   // 36 KB (pad 32->36)

    const int tid  = threadIdx.x;
    const int lane = tid & 63;
    const int w    = tid >> 6;
    const int mBase = blockIdx.y * BM;
    const int eBase = blockIdx.x * BN;
    const int waveM = (w >> 1) * 64;
    const int waveN = (w & 1) * 64;

    f32x4 acc[4][4] = {};

    // staging: lane tid covers (row = tid>>2, 16B chunk = tid&3)
    const int row0 = tid >> 2, cu = tid & 3;
    const unsigned short* aG0 = xb + (size_t)(mBase + row0) * K_ + cu * 8;
    const unsigned short* aG1 = aG0 + (size_t)64 * K_;
    const unsigned short* bG0 = wb + (size_t)(eBase + row0) * K_ + cu * 8;
    const unsigned short* bG1 = bG0 + (size_t)64 * K_;
    // wave-uniform LDS bases (HW adds lane*16B)
    unsigned short* aL0 = As + (size_t)(w * 64) * 8;
    unsigned short* aL1 = As + (size_t)(256 + w * 64) * 8;
    unsigned short* bL0 = Bs + (size_t)(w * 64) * 8;
    unsigned short* bL1 = Bs + (size_t)(256 + w * 64) * 8;

    const int mrow = lane & 15;
    const int kg   = (lane >> 4) * 8;

    for (int k0 = 0; k0 < K_; k0 += BK) {
        __syncthreads();
        gload16(aG0 + k0, aL0);
        gload16(aG1 + k0, aL1);
        gload16(bG0 + k0, bL0);
        gload16(bG1 + k0, bL1);
        __syncthreads();

        bf16x8 af[4], bfr[4];
#pragma unroll
        for (int i = 0; i < 4; i++)
            af[i] = *(const bf16x8*)(As + (size_t)(waveM + i * 16 + mrow) * BK + kg);
#pragma unroll
        for (int j = 0; j < 4; j++)
            bfr[j] = *(const bf16x8*)(Bs + (size_t)(waveN + j * 16 + mrow) * BK + kg);
#pragma unroll
        for (int i = 0; i < 4; i++)
#pragma unroll
            for (int j = 0; j < 4; j++)
                acc[i][j] = __builtin_amdgcn_mfma_f32_16x16x32_bf16(af[i], bfr[j], acc[i][j], 0, 0, 0);
    }

    // ---- epilogue: activation + pack + LDS transpose + coalesced store ----
    // C/D layout: col(e_local) = lane&15, row(m_local) = (lane>>4)*4 + r.
    // Pair lanes (e even/odd) = (hidden, gate) for d = e>>1.
    // Work split: even lane handles r=0,1 ; odd lane handles r=2,3.
    const int q    = lane >> 4;
    const int odd  = lane & 1;
    const int colL = (lane & 15) >> 1;            // 0..7
    unsigned int* EpW = &Ep[w][0][0];

#pragma unroll
    for (int i = 0; i < 4; i++) {
#pragma unroll
        for (int j = 0; j < 4; j++) {
            float o0 = __shfl_xor(acc[i][j][0], 1, 64);
            float o1 = __shfl_xor(acc[i][j][1], 1, 64);
            float o2 = __shfl_xor(acc[i][j][2], 1, 64);
            float o3 = __shfl_xor(acc[i][j][3], 1, 64);
            float m0 = odd ? acc[i][j][2] : acc[i][j][0];
            float m1 = odd ? acc[i][j][3] : acc[i][j][1];
            float p0 = odd ? o2 : o0;
            float p1 = odd ? o3 : o1;
            // even lane: mine=hidden, partner=gate ; odd lane: mine=gate, partner=hidden
            float h0 = odd ? p0 : m0, g0 = odd ? m0 : p0;
            float h1 = odd ? p1 : m1, g1 = odd ? m1 : p1;
            int row = i * 16 + q * 4 + odd * 2;
            int col = j * 8 + colL;
            EpW[(row    ) * 36 + col] = packCV(h0, g0);
            EpW[(row + 1) * 36 + col] = packCV(h1, g1);
        }
    }
    // same-wave LDS readback (no barrier needed) -> coalesced 16B stores
    const int srow = lane >> 3;   // 0..7
    const int schk = lane & 7;    // 0..7
    const size_t dBase = (size_t)((eBase + waveN) >> 1) + schk * 4;
#pragma unroll
    for (int gph = 0; gph < 8; gph++) {
        int row = gph * 8 + srow;
        uint4 valq = *(const uint4*)&EpW[row * 36 + schk * 4];
        size_t m = (size_t)(mBase + waveM + row);
        *(uint4*)(cv + m * D_ + dBase) = valq;
    }
}

// ---------------- blocked scan: h_t = c_t*h_{t-1} + v_t ----------------
// cv packed [M][D] uint = half2(c, v); thread handles d = 2p, 2p+1.
__global__ void seg_reduce(const uint2* __restrict__ cv2,
                           float2* __restrict__ segC, float2* __restrict__ segV) {
    int bj = blockIdx.x;
    int p  = blockIdx.y * 256 + threadIdx.x;      // 0..511
    size_t base = (size_t)bj * SEG * (D_ / 2) + p;
    float C0 = 1.f, V0 = 0.f, C1 = 1.f, V1 = 0.f;
#pragma unroll 4
    for (int s = 0; s < SEG; s++) {
        uint2 u = cv2[base + (size_t)s * (D_ / 2)];
        union { unsigned int u; f16x2 h; } a, b; a.u = u.x; b.u = u.y;
        float c0 = (float)a.h[0], v0 = (float)a.h[1];
        float c1 = (float)b.h[0], v1 = (float)b.h[1];
        V0 = fmaf(c0, V0, v0); C0 *= c0;
        V1 = fmaf(c1, V1, v1); C1 *= c1;
    }
    segC[(size_t)bj * (D_ / 2) + p] = make_float2(C0, C1);
    segV[(size_t)bj * (D_ / 2) + p] = make_float2(V0, V1);
}

__global__ void seg_scan(const float2* __restrict__ segC, const float2* __restrict__ segV,
                         float2* __restrict__ segH) {
    int b = blockIdx.x;
    int p = blockIdx.y * 256 + threadIdx.x;
    float h0 = 0.f, h1 = 0.f;
    for (int j = 0; j < NSEG; j++) {
        size_t idx = ((size_t)b * NSEG + j) * (D_ / 2) + p;
        segH[idx] = make_float2(h0, h1);
        float2 c = segC[idx], v = segV[idx];
        h0 = fmaf(c.x, h0, v.x);
        h1 = fmaf(c.y, h1, v.y);
    }
}

__global__ void seg_apply(const uint2* __restrict__ cv2,
                          const float2* __restrict__ segH, float2* __restrict__ out) {
    int bj = blockIdx.x;
    int p  = blockIdx.y * 256 + threadIdx.x;
    float2 h = segH[(size_t)bj * (D_ / 2) + p];
    float h0 = h.x, h1 = h.y;
    size_t base = (size_t)bj * SEG * (D_ / 2) + p;
#pragma unroll 4
    for (int s = 0; s < SEG; s++) {
        uint2 u = cv2[base + (size_t)s * (D_ / 2)];
        union { unsigned int u; f16x2 h; } a, b; a.u = u.x; b.u = u.y;
        h0 = fmaf((float)a.h[0], h0, (float)a.h[1]);
        h1 = fmaf((float)b.h[0], h1, (float)b.h[1]);
        out[base + (size_t)s * (D_ / 2)] = make_float2(h0, h1);
    }
}

// ---------------- launch ----------------
extern "C" void kernel_launch(void* const* d_in, const int* in_sizes, int n_in,
                              void* d_out, int out_size, void* d_ws, size_t ws_size,
                              hipStream_t stream) {
    const float* x = (const float*)d_in[0];
    const float* wmat = (const float*)d_in[1];
    float* out = (float*)d_out;
    char* ws = (char*)d_ws;

    unsigned short* xb = (unsigned short*)(ws);                   // 32 MB @ 0
    unsigned short* wb = (unsigned short*)(ws + (32u << 20));     //  4 MB @ 32M
    unsigned int*   cv = (unsigned int*)(ws + (36u << 20));       // 64 MB @ 36M
    float* segC = (float*)(ws + (100u << 20));                    //  1 MB @ 100M
    float* segV = (float*)(ws + (101u << 20));                    //  1 MB @ 101M
    float* segH = (float*)(ws + (102u << 20));                    //  1 MB @ 102M

    cvt_x<<<(M_ * K_) / 1024, 256, 0, stream>>>(x, xb, M_ * K_);
    cvt_w<<<(E_ * K_) / 1024, 256, 0, stream>>>(wmat, wb);

    dim3 gg(E_ / BN, M_ / BM);
    gemm_ep<<<gg, 256, 0, stream>>>(xb, wb, cv);

    dim3 ga(B_ * NSEG, D_ / 512);
    seg_reduce<<<ga, 256, 0, stream>>>((const uint2*)cv, (float2*)segC, (float2*)segV);
    dim3 gb(B_, D_ / 512);
    seg_scan<<<gb, 256, 0, stream>>>((const float2*)segC, (const float2*)segV, (float2*)segH);
    seg_apply<<<ga, 256, 0, stream>>>((const uint2*)cv, (const float2*)segH, (float2*)out);
}

// Round 4
// 239.713 us; speedup vs baseline: 1.2160x; 1.0306x over previous
//
#include <hip/hip_runtime.h>
#include <stdint.h>

#define B_ 4
#define S_ 4096
#define D_ 1024
#define E_ 2048          // 2*D
#define K_ 1024
#define M_ (B_*S_)       // 16384
#define SEG 64
#define NSEG (S_/SEG)    // 64 segments per batch, 256 total

typedef __bf16 bf16x8 __attribute__((ext_vector_type(8)));
typedef float  f32x4  __attribute__((ext_vector_type(4)));
typedef _Float16 f16x2 __attribute__((ext_vector_type(2)));

__device__ __forceinline__ unsigned short f2bf(float f) {
    union { float f; unsigned int u; } x; x.f = f;
    unsigned int u = x.u;
    return (unsigned short)((u + 0x7fffu + ((u >> 16) & 1u)) >> 16);
}

__device__ __forceinline__ void gload16(const void* g, void* l) {
    __builtin_amdgcn_global_load_lds(
        (const __attribute__((address_space(1))) void*)(uintptr_t)g,
        (__attribute__((address_space(3))) void*)(uintptr_t)l,
        16, 0, 0);
}

// pack (c = sigmoid(-gate), v = sigmoid(gate)*g(hidden)) as half2 in a uint
__device__ __forceinline__ unsigned int packCV(float hid, float gat) {
    float e  = __expf(gat);
    float c  = __builtin_amdgcn_rcpf(1.f + e);          // sigmoid(-gate)
    float gg = (hid >= 0.f) ? (hid + 0.5f)
                            : __builtin_amdgcn_rcpf(1.f + __expf(-hid));
    float v  = (1.f - c) * gg;                           // sigmoid(gate)*g(hidden)
    union { f16x2 h; unsigned int u; } pk;
    pk.h[0] = (_Float16)c; pk.h[1] = (_Float16)v;
    return pk.u;
}

// ---------------- conversion kernels ----------------
__global__ void cvt_x(const float* __restrict__ x, unsigned short* __restrict__ xb, int n) {
    int i = (blockIdx.x * blockDim.x + threadIdx.x) * 4;
    if (i >= n) return;
    float4 f = *(const float4*)(x + i);
    ushort4 o;
    o.x = f2bf(f.x); o.y = f2bf(f.y); o.z = f2bf(f.z); o.w = f2bf(f.w);
    *(ushort4*)(xb + i) = o;
}

// W' row 2d+g  <-  W row g*D + d   (interleave hidden/gate rows)
__global__ void cvt_w(const float* __restrict__ w, unsigned short* __restrict__ wb) {
    int i = (blockIdx.x * blockDim.x + threadIdx.x) * 4;
    int r = i >> 10;            // K_ = 1024
    int k = i & 1023;
    int d = r >> 1, g = r & 1;
    const float* src = w + (size_t)(g * D_ + d) * K_ + k;
    float4 f = *(const float4*)src;
    ushort4 o;
    o.x = f2bf(f.x); o.y = f2bf(f.y); o.z = f2bf(f.z); o.w = f2bf(f.w);
    *(ushort4*)(wb + i) = o;
}

// ---------------- GEMM + fused epilogue + fused segment reduce ----------------
#define BM 128
#define BN 128
#define BK 32

__global__ __launch_bounds__(256, 2)
void gemm_ep(const unsigned short* __restrict__ xb,
             const unsigned short* __restrict__ wb,
             unsigned int* __restrict__ cv,
             float2* __restrict__ segCV) {
    __shared__ unsigned short As[BM * BK];                 // 8 KB
    __shared__ unsigned short Bs[BN * BK];                 // 8 KB
    __shared__ __align__(16) unsigned int Ep[4][64][36];   // 36 KB (pad 32->36)

    const int tid  = threadIdx.x;
    const int lane = tid & 63;
    const int w    = tid >> 6;
    const int mBase = blockIdx.y * BM;
    const int eBase = blockIdx.x * BN;
    const int waveM = (w >> 1) * 64;
    const int waveN = (w & 1) * 64;

    f32x4 acc[4][4] = {};

    // staging: lane tid covers (row = tid>>2, 16B chunk = tid&3)
    const int row0 = tid >> 2, cu = tid & 3;
    const unsigned short* aG0 = xb + (size_t)(mBase + row0) * K_ + cu * 8;
    const unsigned short* aG1 = aG0 + (size_t)64 * K_;
    const unsigned short* bG0 = wb + (size_t)(eBase + row0) * K_ + cu * 8;
    const unsigned short* bG1 = bG0 + (size_t)64 * K_;
    // wave-uniform LDS bases (HW adds lane*16B)
    unsigned short* aL0 = As + (size_t)(w * 64) * 8;
    unsigned short* aL1 = As + (size_t)(256 + w * 64) * 8;
    unsigned short* bL0 = Bs + (size_t)(w * 64) * 8;
    unsigned short* bL1 = Bs + (size_t)(256 + w * 64) * 8;

    const int mrow = lane & 15;
    const int kg   = (lane >> 4) * 8;

    for (int k0 = 0; k0 < K_; k0 += BK) {
        __syncthreads();
        gload16(aG0 + k0, aL0);
        gload16(aG1 + k0, aL1);
        gload16(bG0 + k0, bL0);
        gload16(bG1 + k0, bL1);
        __syncthreads();

        bf16x8 af[4], bfr[4];
#pragma unroll
        for (int i = 0; i < 4; i++)
            af[i] = *(const bf16x8*)(As + (size_t)(waveM + i * 16 + mrow) * BK + kg);
#pragma unroll
        for (int j = 0; j < 4; j++)
            bfr[j] = *(const bf16x8*)(Bs + (size_t)(waveN + j * 16 + mrow) * BK + kg);
#pragma unroll
        for (int i = 0; i < 4; i++)
#pragma unroll
            for (int j = 0; j < 4; j++)
                acc[i][j] = __builtin_amdgcn_mfma_f32_16x16x32_bf16(af[i], bfr[j], acc[i][j], 0, 0, 0);
    }

    // ---- epilogue: activation + pack + LDS transpose + coalesced store ----
    // C/D layout: col(e_local) = lane&15, row(m_local) = (lane>>4)*4 + r.
    // Pair lanes (e even/odd) = (hidden, gate) for d = e>>1.
    // Work split: even lane handles r=0,1 ; odd lane handles r=2,3.
    const int q    = lane >> 4;
    const int odd  = lane & 1;
    const int colL = (lane & 15) >> 1;            // 0..7
    unsigned int* EpW = &Ep[w][0][0];

#pragma unroll
    for (int i = 0; i < 4; i++) {
#pragma unroll
        for (int j = 0; j < 4; j++) {
            float o0 = __shfl_xor(acc[i][j][0], 1, 64);
            float o1 = __shfl_xor(acc[i][j][1], 1, 64);
            float o2 = __shfl_xor(acc[i][j][2], 1, 64);
            float o3 = __shfl_xor(acc[i][j][3], 1, 64);
            float m0 = odd ? acc[i][j][2] : acc[i][j][0];
            float m1 = odd ? acc[i][j][3] : acc[i][j][1];
            float p0 = odd ? o2 : o0;
            float p1 = odd ? o3 : o1;
            float h0 = odd ? p0 : m0, g0 = odd ? m0 : p0;
            float h1 = odd ? p1 : m1, g1 = odd ? m1 : p1;
            int row = i * 16 + q * 4 + odd * 2;
            int col = j * 8 + colL;
            EpW[(row    ) * 36 + col] = packCV(h0, g0);
            EpW[(row + 1) * 36 + col] = packCV(h1, g1);
        }
    }
    // same-wave LDS readback (no barrier needed) -> coalesced 16B stores
    const int srow = lane >> 3;   // 0..7
    const int schk = lane & 7;    // 0..7
    const size_t dBaseS = (size_t)((eBase + waveN) >> 1) + schk * 4;
#pragma unroll
    for (int gph = 0; gph < 8; gph++) {
        int row = gph * 8 + srow;
        uint4 valq = *(const uint4*)&EpW[row * 36 + schk * 4];
        size_t m = (size_t)(mBase + waveM + row);
        *(uint4*)(cv + m * D_ + dBaseS) = valq;
    }

    // ---- fused segment reduce: two SEG=64 segments per block ----
    // Ep[w][r][c] <-> m_local = (w>>1)*64 + r, d_local = (w&1)*32 + c
    __syncthreads();                      // Ep fully written; As/Bs dead -> reuse
    float* scratch = (float*)As;          // [4][64][2] floats = 2 KB

    {
        const int dl = tid & 63;          // d_local 0..63
        const int qt = tid >> 6;          // quarter 0..3 (rows qt*32 .. +31)
        const int wq = (qt >> 1) * 2 + (dl >> 5);
        const int rBase = (qt & 1) * 32;
        const int c = dl & 31;
        const unsigned int* src = &Ep[wq][rBase][c];
        float C = 1.f, V = 0.f;
#pragma unroll 8
        for (int rr = 0; rr < 32; rr++) {
            union { unsigned int u; f16x2 h; } uu;
            uu.u = src[rr * 36];
            float cc = (float)uu.h[0], vv = (float)uu.h[1];
            V = fmaf(cc, V, vv);
            C *= cc;
        }
        scratch[(qt * 64 + dl) * 2 + 0] = C;
        scratch[(qt * 64 + dl) * 2 + 1] = V;
    }
    __syncthreads();
    if (tid < 128) {
        const int k  = tid >> 6;          // which SEG=64 segment (0 or 1)
        const int dl = tid & 63;
        float C0 = scratch[((2 * k    ) * 64 + dl) * 2 + 0];
        float V0 = scratch[((2 * k    ) * 64 + dl) * 2 + 1];
        float C1 = scratch[((2 * k + 1) * 64 + dl) * 2 + 0];
        float V1 = scratch[((2 * k + 1) * 64 + dl) * 2 + 1];
        int bj = blockIdx.y * 2 + k;                 // global segment index 0..255
        int dg = blockIdx.x * 64 + dl;
        segCV[(size_t)bj * D_ + dg] = make_float2(C0 * C1, fmaf(C1, V0, V1));
    }
}

// ---------------- fused scan + apply ----------------
// block = (segment bj, d-chunk). Catch-up scan over predecessor segments
// (L2-hot 2MB segCV), then apply over this segment's 64 rows.
__global__ void scan_apply(const uint2* __restrict__ cv2,
                           const float2* __restrict__ segCV,
                           float2* __restrict__ out2) {
    const int bj = blockIdx.x;                    // 0..255
    const int jFirst = bj & ~(NSEG - 1);          // first segment of this batch
    const int p = blockIdx.y * 256 + threadIdx.x; // 0..511 (d pair)

    float h0 = 0.f, h1 = 0.f;
    const float4* sc4 = (const float4*)segCV;     // (C0,V0,C1,V1) per d-pair
    for (int j = jFirst; j < bj; j++) {
        float4 s = sc4[(size_t)j * (D_ / 2) + p];
        h0 = fmaf(s.x, h0, s.y);
        h1 = fmaf(s.z, h1, s.w);
    }

    size_t base = (size_t)bj * SEG * (D_ / 2) + p;
#pragma unroll 4
    for (int s = 0; s < SEG; s++) {
        uint2 u = cv2[base + (size_t)s * (D_ / 2)];
        union { unsigned int u; f16x2 h; } a, b; a.u = u.x; b.u = u.y;
        h0 = fmaf((float)a.h[0], h0, (float)a.h[1]);
        h1 = fmaf((float)b.h[0], h1, (float)b.h[1]);
        out2[base + (size_t)s * (D_ / 2)] = make_float2(h0, h1);
    }
}

// ---------------- launch ----------------
extern "C" void kernel_launch(void* const* d_in, const int* in_sizes, int n_in,
                              void* d_out, int out_size, void* d_ws, size_t ws_size,
                              hipStream_t stream) {
    const float* x = (const float*)d_in[0];
    const float* wmat = (const float*)d_in[1];
    float* out = (float*)d_out;
    char* ws = (char*)d_ws;

    unsigned short* xb = (unsigned short*)(ws);                   // 32 MB @ 0
    unsigned short* wb = (unsigned short*)(ws + (32u << 20));     //  4 MB @ 32M
    unsigned int*   cv = (unsigned int*)(ws + (36u << 20));       // 64 MB @ 36M
    float2*      segCV = (float2*)(ws + (100u << 20));            //  2 MB @ 100M

    cvt_x<<<(M_ * K_) / 1024, 256, 0, stream>>>(x, xb, M_ * K_);
    cvt_w<<<(E_ * K_) / 1024, 256, 0, stream>>>(wmat, wb);

    dim3 gg(E_ / BN, M_ / BM);
    gemm_ep<<<gg, 256, 0, stream>>>(xb, wb, cv, segCV);

    dim3 ga(B_ * NSEG, D_ / 512);
    scan_apply<<<ga, 256, 0, stream>>>((const uint2*)cv, (const float2*)segCV,
                                       (float2*)out);
}

// Round 5
// 233.536 us; speedup vs baseline: 1.2482x; 1.0265x over previous
//
#include <hip/hip_runtime.h>
#include <stdint.h>

#define B_ 4
#define S_ 4096
#define D_ 1024
#define E_ 2048          // 2*D
#define K_ 1024
#define M_ (B_*S_)       // 16384
#define SEG 64
#define NSEG (S_/SEG)    // 64 segments per batch, 256 total

typedef __bf16 bf16x8 __attribute__((ext_vector_type(8)));
typedef float  f32x4  __attribute__((ext_vector_type(4)));
typedef _Float16 f16x2 __attribute__((ext_vector_type(2)));

__device__ __forceinline__ unsigned short f2bf(float f) {
    union { float f; unsigned int u; } x; x.f = f;
    unsigned int u = x.u;
    return (unsigned short)((u + 0x7fffu + ((u >> 16) & 1u)) >> 16);
}

__device__ __forceinline__ void gload16(const void* g, void* l) {
    __builtin_amdgcn_global_load_lds(
        (const __attribute__((address_space(1))) void*)(uintptr_t)g,
        (__attribute__((address_space(3))) void*)(uintptr_t)l,
        16, 0, 0);
}

// pack (c = sigmoid(-gate), v = sigmoid(gate)*g(hidden)) as half2 in a uint
__device__ __forceinline__ unsigned int packCV(float hid, float gat) {
    float e  = __expf(gat);
    float c  = __builtin_amdgcn_rcpf(1.f + e);          // sigmoid(-gate)
    float gg = (hid >= 0.f) ? (hid + 0.5f)
                            : __builtin_amdgcn_rcpf(1.f + __expf(-hid));
    float v  = (1.f - c) * gg;                           // sigmoid(gate)*g(hidden)
    union { f16x2 h; unsigned int u; } pk;
    pk.h[0] = (_Float16)c; pk.h[1] = (_Float16)v;
    return pk.u;
}

// ---------------- merged conversion kernel ----------------
// blocks [0, 16384): x -> bf16 ; blocks [16384, 18432): W interleave -> bf16
__global__ void cvt_xw(const float* __restrict__ x, unsigned short* __restrict__ xb,
                       const float* __restrict__ w, unsigned short* __restrict__ wb) {
    int b = blockIdx.x;
    if (b < 16384) {
        int i = (b * 256 + threadIdx.x) * 4;
        float4 f = *(const float4*)(x + i);
        ushort4 o;
        o.x = f2bf(f.x); o.y = f2bf(f.y); o.z = f2bf(f.z); o.w = f2bf(f.w);
        *(ushort4*)(xb + i) = o;
    } else {
        int i = ((b - 16384) * 256 + threadIdx.x) * 4;   // index into [E_, K_]
        int r = i >> 10;            // K_ = 1024
        int k = i & 1023;
        int d = r >> 1, g = r & 1;
        const float* src = w + (size_t)(g * D_ + d) * K_ + k;
        float4 f = *(const float4*)src;
        ushort4 o;
        o.x = f2bf(f.x); o.y = f2bf(f.y); o.z = f2bf(f.z); o.w = f2bf(f.w);
        *(ushort4*)(wb + i) = o;
    }
}

// ---------------- GEMM + fused epilogue + fused segment reduce ----------------
#define BM 128
#define BN 128
#define BK 32

__global__ __launch_bounds__(256, 2)
void gemm_ep(const unsigned short* __restrict__ xb,
             const unsigned short* __restrict__ wb,
             unsigned int* __restrict__ cv,
             float2* __restrict__ segCV) {
    __shared__ unsigned short As[BM * BK];                 // 8 KB
    __shared__ unsigned short Bs[BN * BK];                 // 8 KB
    __shared__ __align__(16) unsigned int Ep[4][64][36];   // 36 KB (pad 32->36)

    // XCD-aware swizzle: XCD k (= l&7) owns mB in [16k, 16k+16), iterated as
    // four 8mB x 8eB generations -> per-XCD L2 working set ~= 2MB xb + 2MB wb.
    const int l    = blockIdx.x;        // 0..2047
    const int xcd  = l & 7;
    const int r    = l >> 3;            // 0..255
    const int sub  = r >> 6;            // 0..3
    const int win  = r & 63;
    const int eB   = (sub & 1) * 8 + (win & 7);          // 0..15
    const int mB   = xcd * 16 + (sub >> 1) * 8 + (win >> 3);  // 0..127
    const int mBase = mB * BM;
    const int eBase = eB * BN;

    const int tid  = threadIdx.x;
    const int lane = tid & 63;
    const int w    = tid >> 6;
    const int waveM = (w >> 1) * 64;
    const int waveN = (w & 1) * 64;

    f32x4 acc[4][4] = {};

    // staging: lane tid covers (row = tid>>2, 16B chunk = tid&3)
    const int row0 = tid >> 2, cu = tid & 3;
    const unsigned short* aG0 = xb + (size_t)(mBase + row0) * K_ + cu * 8;
    const unsigned short* aG1 = aG0 + (size_t)64 * K_;
    const unsigned short* bG0 = wb + (size_t)(eBase + row0) * K_ + cu * 8;
    const unsigned short* bG1 = bG0 + (size_t)64 * K_;
    // wave-uniform LDS bases (HW adds lane*16B)
    unsigned short* aL0 = As + (size_t)(w * 64) * 8;
    unsigned short* aL1 = As + (size_t)(256 + w * 64) * 8;
    unsigned short* bL0 = Bs + (size_t)(w * 64) * 8;
    unsigned short* bL1 = Bs + (size_t)(256 + w * 64) * 8;

    const int mrow = lane & 15;
    const int kg   = (lane >> 4) * 8;

    for (int k0 = 0; k0 < K_; k0 += BK) {
        __syncthreads();
        gload16(aG0 + k0, aL0);
        gload16(aG1 + k0, aL1);
        gload16(bG0 + k0, bL0);
        gload16(bG1 + k0, bL1);
        __syncthreads();

        bf16x8 af[4], bfr[4];
#pragma unroll
        for (int i = 0; i < 4; i++)
            af[i] = *(const bf16x8*)(As + (size_t)(waveM + i * 16 + mrow) * BK + kg);
#pragma unroll
        for (int j = 0; j < 4; j++)
            bfr[j] = *(const bf16x8*)(Bs + (size_t)(waveN + j * 16 + mrow) * BK + kg);
#pragma unroll
        for (int i = 0; i < 4; i++)
#pragma unroll
            for (int j = 0; j < 4; j++)
                acc[i][j] = __builtin_amdgcn_mfma_f32_16x16x32_bf16(af[i], bfr[j], acc[i][j], 0, 0, 0);
    }

    // ---- epilogue: activation + pack + LDS transpose + coalesced store ----
    const int q    = lane >> 4;
    const int odd  = lane & 1;
    const int colL = (lane & 15) >> 1;            // 0..7
    unsigned int* EpW = &Ep[w][0][0];

#pragma unroll
    for (int i = 0; i < 4; i++) {
#pragma unroll
        for (int j = 0; j < 4; j++) {
            float o0 = __shfl_xor(acc[i][j][0], 1, 64);
            float o1 = __shfl_xor(acc[i][j][1], 1, 64);
            float o2 = __shfl_xor(acc[i][j][2], 1, 64);
            float o3 = __shfl_xor(acc[i][j][3], 1, 64);
            float m0 = odd ? acc[i][j][2] : acc[i][j][0];
            float m1 = odd ? acc[i][j][3] : acc[i][j][1];
            float p0 = odd ? o2 : o0;
            float p1 = odd ? o3 : o1;
            float h0 = odd ? p0 : m0, g0 = odd ? m0 : p0;
            float h1 = odd ? p1 : m1, g1 = odd ? m1 : p1;
            int row = i * 16 + q * 4 + odd * 2;
            int col = j * 8 + colL;
            EpW[(row    ) * 36 + col] = packCV(h0, g0);
            EpW[(row + 1) * 36 + col] = packCV(h1, g1);
        }
    }
    // same-wave LDS readback (no barrier needed) -> coalesced 16B stores
    const int srow = lane >> 3;   // 0..7
    const int schk = lane & 7;    // 0..7
    const size_t dBaseS = (size_t)((eBase + waveN) >> 1) + schk * 4;
#pragma unroll
    for (int gph = 0; gph < 8; gph++) {
        int row = gph * 8 + srow;
        uint4 valq = *(const uint4*)&EpW[row * 36 + schk * 4];
        size_t m = (size_t)(mBase + waveM + row);
        *(uint4*)(cv + m * D_ + dBaseS) = valq;
    }

    // ---- fused segment reduce: two SEG=64 segments per block ----
    __syncthreads();                      // Ep fully written; As/Bs dead -> reuse
    float* scratch = (float*)As;          // [4][64][2] floats = 2 KB

    {
        const int dl = tid & 63;          // d_local 0..63
        const int qt = tid >> 6;          // quarter 0..3 (rows qt*32 .. +31)
        const int wq = (qt >> 1) * 2 + (dl >> 5);
        const int rBase = (qt & 1) * 32;
        const int c = dl & 31;
        const unsigned int* src = &Ep[wq][rBase][c];
        float C = 1.f, V = 0.f;
#pragma unroll 8
        for (int rr = 0; rr < 32; rr++) {
            union { unsigned int u; f16x2 h; } uu;
            uu.u = src[rr * 36];
            float cc = (float)uu.h[0], vv = (float)uu.h[1];
            V = fmaf(cc, V, vv);
            C *= cc;
        }
        scratch[(qt * 64 + dl) * 2 + 0] = C;
        scratch[(qt * 64 + dl) * 2 + 1] = V;
    }
    __syncthreads();
    if (tid < 128) {
        const int k  = tid >> 6;          // which SEG=64 segment (0 or 1)
        const int dl = tid & 63;
        float C0 = scratch[((2 * k    ) * 64 + dl) * 2 + 0];
        float V0 = scratch[((2 * k    ) * 64 + dl) * 2 + 1];
        float C1 = scratch[((2 * k + 1) * 64 + dl) * 2 + 0];
        float V1 = scratch[((2 * k + 1) * 64 + dl) * 2 + 1];
        int bj = mB * 2 + k;                      // global segment index 0..255
        int dg = (eBase >> 1) + dl;
        segCV[(size_t)bj * D_ + dg] = make_float2(C0 * C1, fmaf(C1, V0, V1));
    }
}

// ---------------- segCV prescan: segH[j][d] = h before segment j ----------------
// grid (4 batches, 4 dgroups) x 256 threads; serial over 64 segments (L2-hot).
__global__ void seg_scan(const float2* __restrict__ segCV, float* __restrict__ segH) {
    int b = blockIdx.x;
    int d = blockIdx.y * 256 + threadIdx.x;
    float h = 0.f;
    for (int j0 = 0; j0 < NSEG; j0 += 8) {
        float2 s[8];
#pragma unroll
        for (int t = 0; t < 8; t++)
            s[t] = segCV[(size_t)(b * NSEG + j0 + t) * D_ + d];
#pragma unroll
        for (int t = 0; t < 8; t++) {
            segH[(size_t)(b * NSEG + j0 + t) * D_ + d] = h;
            h = fmaf(s[t].x, h, s[t].y);
        }
    }
}

// ---------------- streaming apply: h_t = c_t*h_{t-1} + v_t ----------------
__global__ void seg_apply(const uint2* __restrict__ cv2,
                          const float2* __restrict__ segH2, float2* __restrict__ out2) {
    const int bj = blockIdx.x;                    // 0..255
    const int p  = blockIdx.y * 256 + threadIdx.x; // 0..511 (d pair)

    float2 hs = segH2[(size_t)bj * (D_ / 2) + p];
    float h0 = hs.x, h1 = hs.y;
    size_t base = (size_t)bj * SEG * (D_ / 2) + p;
    for (int s0 = 0; s0 < SEG; s0 += 8) {
        uint2 u[8];
#pragma unroll
        for (int t = 0; t < 8; t++)
            u[t] = cv2[base + (size_t)(s0 + t) * (D_ / 2)];
        float2 o[8];
#pragma unroll
        for (int t = 0; t < 8; t++) {
            union { unsigned int u; f16x2 h; } a, b; a.u = u[t].x; b.u = u[t].y;
            h0 = fmaf((float)a.h[0], h0, (float)a.h[1]);
            h1 = fmaf((float)b.h[0], h1, (float)b.h[1]);
            o[t] = make_float2(h0, h1);
        }
#pragma unroll
        for (int t = 0; t < 8; t++)
            out2[base + (size_t)(s0 + t) * (D_ / 2)] = o[t];
    }
}

// ---------------- launch ----------------
extern "C" void kernel_launch(void* const* d_in, const int* in_sizes, int n_in,
                              void* d_out, int out_size, void* d_ws, size_t ws_size,
                              hipStream_t stream) {
    const float* x = (const float*)d_in[0];
    const float* wmat = (const float*)d_in[1];
    float* out = (float*)d_out;
    char* ws = (char*)d_ws;

    unsigned short* xb = (unsigned short*)(ws);                   // 32 MB @ 0
    unsigned short* wb = (unsigned short*)(ws + (32u << 20));     //  4 MB @ 32M
    unsigned int*   cv = (unsigned int*)(ws + (36u << 20));       // 64 MB @ 36M
    float2*      segCV = (float2*)(ws + (100u << 20));            //  2 MB @ 100M
    float*        segH = (float*)(ws + (102u << 20));             //  1 MB @ 102M

    cvt_xw<<<18432, 256, 0, stream>>>(x, xb, wmat, wb);

    gemm_ep<<<2048, 256, 0, stream>>>(xb, wb, cv, segCV);

    dim3 gs(B_, D_ / 256);
    seg_scan<<<gs, 256, 0, stream>>>((const float2*)segCV, segH);

    dim3 ga(B_ * NSEG, D_ / 512);
    seg_apply<<<ga, 256, 0, stream>>>((const uint2*)cv, (const float2*)segH,
                                      (float2*)out);
}